// Round 1
// baseline (762.187 us; speedup 1.0000x reference)
//
#include <hip/hip_runtime.h>

namespace {
constexpr int T_STEPS = 25;
constexpr int IN_F    = 14;
constexpr int H       = 24;
constexpr int NSTEP   = 13;   // WINDOW_HALF + 1 steps reach the center state
constexpr int NB_BLK  = 128;  // batch elements per block (x2 directions = 256 threads)
constexpr int NCLS    = 4;
}

__device__ __forceinline__ float fast_rcp(float x) { return __builtin_amdgcn_rcpf(x); }
__device__ __forceinline__ float fast_sigmoid(float x) { return fast_rcp(1.0f + __expf(-x)); }
// tanh(x) = 1 - 2/(exp(2x)+1); saturates correctly for |x| large (exp -> 0 or inf)
__device__ __forceinline__ float fast_tanh(float x) { return 1.0f - 2.0f * fast_rcp(1.0f + __expf(2.0f * x)); }

__global__ __launch_bounds__(256, 2)
void bilstm_head_kernel(const float* __restrict__ x,
                        const float* __restrict__ w_ih_f, const float* __restrict__ w_hh_f,
                        const float* __restrict__ b_ih_f, const float* __restrict__ b_hh_f,
                        const float* __restrict__ w_ih_b, const float* __restrict__ w_hh_b,
                        const float* __restrict__ b_ih_b, const float* __restrict__ b_hh_b,
                        const float* __restrict__ head_w, const float* __restrict__ head_b,
                        float* __restrict__ out, int B)
{
    __shared__ float s_h[NB_BLK][2 * H + 1];  // +1 pad: stride 49 breaks bank aliasing
    __shared__ float s_hw[NCLS * 2 * H];
    __shared__ float s_hb[NCLS];

    const int tid = threadIdx.x;
    if (tid < NCLS * 2 * H) s_hw[tid] = head_w[tid];
    if (tid < NCLS)         s_hb[tid] = head_b[tid];

    // dir is uniform per wave (tid 0..127 = waves 0,1 fwd; 128..255 = waves 2,3 bwd).
    // readfirstlane forces it into an SGPR so all weight pointers/loads scalarize.
    const int dir = __builtin_amdgcn_readfirstlane(tid >> 7);
    const int bl  = tid & (NB_BLK - 1);
    const int b   = blockIdx.x * NB_BLK + bl;

    const float* __restrict__ w_ih = dir ? w_ih_b : w_ih_f;
    const float* __restrict__ w_hh = dir ? w_hh_b : w_hh_f;
    const float* __restrict__ b_ih = dir ? b_ih_b : b_ih_f;
    const float* __restrict__ b_hh = dir ? b_hh_b : b_hh_f;
    const int tstep = dir ? -IN_F : IN_F;  // walk time forward or backward

    if (b < B) {
        const float* xp = x + ((size_t)b * T_STEPS + (dir ? (T_STEPS - 1) : 0)) * IN_F;

        float h[H], c[H];
        #pragma unroll
        for (int k = 0; k < H; ++k) { h[k] = 0.0f; c[k] = 0.0f; }

        float xv[IN_F];
        #pragma unroll
        for (int f = 0; f < IN_F; ++f) xv[f] = xp[f];

        #pragma unroll 1   // keep the step loop rolled: body is ~4k instrs after k-unroll
        for (int s = 0; s < NSTEP; ++s) {
            // prefetch next step's x under the long compute body
            float xn[IN_F];
            if (s < NSTEP - 1) {
                const float* xq = xp + tstep;
                #pragma unroll
                for (int f = 0; f < IN_F; ++f) xn[f] = xq[f];
            }

            float hn[H];
            #pragma unroll
            for (int k = 0; k < H; ++k) {
                // 4 independent accumulators (i,f,g,o) -> ILP covers FMA latency
                float a0 = b_ih[k]         + b_hh[k];
                float a1 = b_ih[H + k]     + b_hh[H + k];
                float a2 = b_ih[2*H + k]   + b_hh[2*H + k];
                float a3 = b_ih[3*H + k]   + b_hh[3*H + k];

                const float* wi0 = w_ih + k * IN_F;
                const float* wi1 = w_ih + (H + k) * IN_F;
                const float* wi2 = w_ih + (2*H + k) * IN_F;
                const float* wi3 = w_ih + (3*H + k) * IN_F;
                #pragma unroll
                for (int f = 0; f < IN_F; ++f) {
                    const float xf = xv[f];
                    a0 += xf * wi0[f];
                    a1 += xf * wi1[f];
                    a2 += xf * wi2[f];
                    a3 += xf * wi3[f];
                }

                const float* wh0 = w_hh + k * H;
                const float* wh1 = w_hh + (H + k) * H;
                const float* wh2 = w_hh + (2*H + k) * H;
                const float* wh3 = w_hh + (3*H + k) * H;
                #pragma unroll
                for (int j = 0; j < H; ++j) {
                    const float hj = h[j];
                    a0 += hj * wh0[j];
                    a1 += hj * wh1[j];
                    a2 += hj * wh2[j];
                    a3 += hj * wh3[j];
                }

                const float ig = fast_sigmoid(a0);
                const float fg = fast_sigmoid(a1);
                const float gg = fast_tanh(a2);
                const float og = fast_sigmoid(a3);
                const float cn = fg * c[k] + ig * gg;
                c[k]  = cn;
                hn[k] = og * fast_tanh(cn);
            }
            #pragma unroll
            for (int k = 0; k < H; ++k) h[k] = hn[k];

            if (s < NSTEP - 1) {
                #pragma unroll
                for (int f = 0; f < IN_F; ++f) xv[f] = xn[f];
                xp += tstep;
            }
        }

        // deposit this direction's center hidden state
        #pragma unroll
        for (int k = 0; k < H; ++k) s_h[bl][dir * H + k] = h[k];
    }

    __syncthreads();

    // fused head: 128 batch x 4 classes = 512 outputs per block, 2 per thread
    for (int o = tid; o < NB_BLK * NCLS; o += 256) {
        const int blo = o >> 2;
        const int cls = o & 3;
        const int bg  = blockIdx.x * NB_BLK + blo;
        if (bg < B) {
            float acc = s_hb[cls];
            const float* hv = s_h[blo];
            const float* wv = s_hw + cls * 2 * H;
            #pragma unroll
            for (int m = 0; m < 2 * H; ++m) acc += hv[m] * wv[m];
            out[(size_t)bg * NCLS + cls] = acc;
        }
    }
}

extern "C" void kernel_launch(void* const* d_in, const int* in_sizes, int n_in,
                              void* d_out, int out_size, void* d_ws, size_t ws_size,
                              hipStream_t stream)
{
    const float* x      = (const float*)d_in[0];
    const float* w_ih_f = (const float*)d_in[1];
    const float* w_hh_f = (const float*)d_in[2];
    const float* b_ih_f = (const float*)d_in[3];
    const float* b_hh_f = (const float*)d_in[4];
    const float* w_ih_b = (const float*)d_in[5];
    const float* w_hh_b = (const float*)d_in[6];
    const float* b_ih_b = (const float*)d_in[7];
    const float* b_hh_b = (const float*)d_in[8];
    const float* head_w = (const float*)d_in[9];
    const float* head_b = (const float*)d_in[10];
    float* out = (float*)d_out;

    const int B = in_sizes[0] / (T_STEPS * IN_F);
    const int grid = (B + NB_BLK - 1) / NB_BLK;
    hipLaunchKernelGGL(bilstm_head_kernel, dim3(grid), dim3(256), 0, stream,
                       x, w_ih_f, w_hh_f, b_ih_f, b_hh_f,
                       w_ih_b, w_hh_b, b_ih_b, b_hh_b,
                       head_w, head_b, out, B);
}

// Round 2
// 589.158 us; speedup vs baseline: 1.2937x; 1.2937x over previous
//
#include <hip/hip_runtime.h>

namespace {
constexpr int T_STEPS = 25;
constexpr int IN_F    = 14;
constexpr int H       = 24;
constexpr int NSTEP   = 13;   // WINDOW_HALF + 1 steps reach the center state
constexpr int NB_BLK  = 128;  // batch elements per block (x2 directions = 256 threads)
constexpr int NCLS    = 4;

// Packed weight stream layout (floats), per k-unit block of 156 floats:
//   [0..3]    biases: {bi_i+bh_i, bi_f+bh_f, bi_g+bh_g, bi_o+bh_o}
//   [4..31]   x-weights (i,f) interleaved:  {wi_i[f], wi_f[f]} for f=0..13
//   [32..59]  x-weights (g,o) interleaved
//   [60..107] h-weights (i,f) interleaved:  {u_i[j], u_f[j]} for j=0..23
//   [108..155] h-weights (g,o) interleaved
constexpr int PK_K   = 156;          // floats per k-unit
constexpr int PK_DIR = H * PK_K;     // 3744 floats per direction
}

typedef float v2f __attribute__((ext_vector_type(2)));

__device__ __forceinline__ float fast_rcp(float x) { return __builtin_amdgcn_rcpf(x); }
__device__ __forceinline__ float fast_sigmoid(float x) { return fast_rcp(1.0f + __expf(-x)); }
// tanh(x) = 1 - 2/(exp(2x)+1); saturates correctly for |x| large
__device__ __forceinline__ float fast_tanh(float x) { return 1.0f - 2.0f * fast_rcp(1.0f + __expf(2.0f * x)); }

__global__ void pack_weights_kernel(const float* __restrict__ w_ih_f, const float* __restrict__ w_hh_f,
                                    const float* __restrict__ b_ih_f, const float* __restrict__ b_hh_f,
                                    const float* __restrict__ w_ih_b, const float* __restrict__ w_hh_b,
                                    const float* __restrict__ b_ih_b, const float* __restrict__ b_hh_b,
                                    float* __restrict__ ws)
{
    const int t = threadIdx.x;          // one thread per (dir, k)
    if (t >= 2 * H) return;
    const int dir = t / H;
    const int k   = t % H;
    const float* wih = dir ? w_ih_b : w_ih_f;
    const float* whh = dir ? w_hh_b : w_hh_f;
    const float* bih = dir ? b_ih_b : b_ih_f;
    const float* bhh = dir ? b_hh_b : b_hh_f;

    float* o = ws + dir * PK_DIR + k * PK_K;
    o[0] = bih[k]       + bhh[k];
    o[1] = bih[H + k]   + bhh[H + k];
    o[2] = bih[2*H + k] + bhh[2*H + k];
    o[3] = bih[3*H + k] + bhh[3*H + k];
    for (int f = 0; f < IN_F; ++f) {
        o[4  + 2*f]     = wih[k * IN_F + f];
        o[4  + 2*f + 1] = wih[(H + k) * IN_F + f];
        o[32 + 2*f]     = wih[(2*H + k) * IN_F + f];
        o[32 + 2*f + 1] = wih[(3*H + k) * IN_F + f];
    }
    for (int j = 0; j < H; ++j) {
        o[60  + 2*j]     = whh[k * H + j];
        o[60  + 2*j + 1] = whh[(H + k) * H + j];
        o[108 + 2*j]     = whh[(2*H + k) * H + j];
        o[108 + 2*j + 1] = whh[(3*H + k) * H + j];
    }
}

__global__ __launch_bounds__(256, 2)
void bilstm_head_kernel(const float* __restrict__ x,
                        const float* __restrict__ wpk,   // packed weights in d_ws
                        const float* __restrict__ head_w, const float* __restrict__ head_b,
                        float* __restrict__ out, int B)
{
    __shared__ float s_h[NB_BLK][2 * H + 1];
    __shared__ float s_hw[NCLS * 2 * H];
    __shared__ float s_hb[NCLS];

    const int tid = threadIdx.x;
    if (tid < NCLS * 2 * H) s_hw[tid] = head_w[tid];
    if (tid < NCLS)         s_hb[tid] = head_b[tid];

    // dir uniform per wave; readfirstlane pins it to an SGPR so the packed
    // weight pointer (and every load off it) scalarizes to s_load.
    const int dir = __builtin_amdgcn_readfirstlane(tid >> 7);
    const int bl  = tid & (NB_BLK - 1);
    const int b   = blockIdx.x * NB_BLK + bl;

    const v2f* __restrict__ wbase = (const v2f*)(wpk + dir * PK_DIR);
    const int tstep = dir ? -IN_F : IN_F;

    if (b < B) {
        const float* xp = x + ((size_t)b * T_STEPS + (dir ? (T_STEPS - 1) : 0)) * IN_F;

        float h[H], c[H];
        #pragma unroll
        for (int k = 0; k < H; ++k) { h[k] = 0.0f; c[k] = 0.0f; }

        float xv[IN_F];
        #pragma unroll
        for (int f = 0; f < IN_F; ++f) xv[f] = xp[f];

        #pragma unroll 1
        for (int s = 0; s < NSTEP; ++s) {
            // prefetch next step's x under the compute body
            float xn[IN_F];
            if (s < NSTEP - 1) {
                const float* xq = xp + tstep;
                #pragma unroll
                for (int f = 0; f < IN_F; ++f) xn[f] = xq[f];
            }

            float hn[H];
            const v2f* wp = wbase;   // sequential uniform stream, 78 v2f per k
            #pragma unroll
            for (int k = 0; k < H; ++k) {
                v2f aif = wp[0];                 // {bias_i, bias_f}
                v2f ago = wp[1];                 // {bias_g, bias_o}
                const v2f* pif = wp + 2;         // 14 pairs
                const v2f* pgo = wp + 16;        // 14 pairs
                const v2f* qif = wp + 30;        // 24 pairs
                const v2f* qgo = wp + 54;        // 24 pairs

                #pragma unroll
                for (int f = 0; f < IN_F; ++f) {
                    const v2f xs = {xv[f], xv[f]};
                    aif += xs * pif[f];          // v_pk_fma_f32: 2 MACs/instr
                    ago += xs * pgo[f];
                }
                #pragma unroll
                for (int j = 0; j < H; ++j) {
                    const v2f hs = {h[j], h[j]};
                    aif += hs * qif[j];
                    ago += hs * qgo[j];
                }
                wp += 78;

                const float ig = fast_sigmoid(aif.x);
                const float fg = fast_sigmoid(aif.y);
                const float gg = fast_tanh(ago.x);
                const float og = fast_sigmoid(ago.y);
                const float cn = fg * c[k] + ig * gg;
                c[k]  = cn;
                hn[k] = og * fast_tanh(cn);
            }
            #pragma unroll
            for (int k = 0; k < H; ++k) h[k] = hn[k];

            if (s < NSTEP - 1) {
                #pragma unroll
                for (int f = 0; f < IN_F; ++f) xv[f] = xn[f];
                xp += tstep;
            }
        }

        #pragma unroll
        for (int k = 0; k < H; ++k) s_h[bl][dir * H + k] = h[k];
    }

    __syncthreads();

    for (int o = tid; o < NB_BLK * NCLS; o += 256) {
        const int blo = o >> 2;
        const int cls = o & 3;
        const int bg  = blockIdx.x * NB_BLK + blo;
        if (bg < B) {
            float acc = s_hb[cls];
            const float* hv = s_h[blo];
            const float* wv = s_hw + cls * 2 * H;
            #pragma unroll
            for (int m = 0; m < 2 * H; ++m) acc += hv[m] * wv[m];
            out[(size_t)bg * NCLS + cls] = acc;
        }
    }
}

extern "C" void kernel_launch(void* const* d_in, const int* in_sizes, int n_in,
                              void* d_out, int out_size, void* d_ws, size_t ws_size,
                              hipStream_t stream)
{
    const float* x      = (const float*)d_in[0];
    const float* w_ih_f = (const float*)d_in[1];
    const float* w_hh_f = (const float*)d_in[2];
    const float* b_ih_f = (const float*)d_in[3];
    const float* b_hh_f = (const float*)d_in[4];
    const float* w_ih_b = (const float*)d_in[5];
    const float* w_hh_b = (const float*)d_in[6];
    const float* b_ih_b = (const float*)d_in[7];
    const float* b_hh_b = (const float*)d_in[8];
    const float* head_w = (const float*)d_in[9];
    const float* head_b = (const float*)d_in[10];
    float* out = (float*)d_out;
    float* ws  = (float*)d_ws;

    const int B = in_sizes[0] / (T_STEPS * IN_F);
    const int grid = (B + NB_BLK - 1) / NB_BLK;

    hipLaunchKernelGGL(pack_weights_kernel, dim3(1), dim3(64), 0, stream,
                       w_ih_f, w_hh_f, b_ih_f, b_hh_f,
                       w_ih_b, w_hh_b, b_ih_b, b_hh_b, ws);
    hipLaunchKernelGGL(bilstm_head_kernel, dim3(grid), dim3(256), 0, stream,
                       x, ws, head_w, head_b, out, B);
}

// Round 3
// 241.757 us; speedup vs baseline: 3.1527x; 2.4370x over previous
//
#include <hip/hip_runtime.h>
#include <math.h>

typedef __attribute__((ext_vector_type(8))) short frag8;     // 8 bf16 = 4 VGPRs
typedef __attribute__((ext_vector_type(4))) float f4;
typedef __attribute__((ext_vector_type(4))) unsigned int u4;
typedef __attribute__((ext_vector_type(2))) float f2;

namespace {
constexpr int T_STEPS = 25;
constexpr int IN_F    = 14;
constexpr int H       = 24;
constexpr int NSTEP   = 13;
// d_ws layout:
//   shorts [0 .. 32768): B-fragments, indexed ((dir*4+set)*8+tile)*64 + lane, 8 shorts each
//     set 0 = Wx_hi (rows k0..13 and k14..27 both = Wx_hi, 28..31 = 0)
//     set 1 = Wx_lo (same row duplication)
//     set 2 = Wh_hi (rows k0..23, 24..31 = 0)
//     set 3 = Wh_lo
//   floats [16384 .. 16640): bias[dir][128] by gate-row r = g*32+u (pad u>=24 -> 0)
}

__device__ __forceinline__ unsigned short bf16_rne(float f) {
    unsigned int u = __float_as_uint(f);
    u += 0x7fff + ((u >> 16) & 1);
    return (unsigned short)(u >> 16);
}
__device__ __forceinline__ float bf16_to_f(unsigned short s) {
    return __uint_as_float(((unsigned int)s) << 16);
}
__device__ __forceinline__ float fast_rcp(float x) { return __builtin_amdgcn_rcpf(x); }
__device__ __forceinline__ float fsig(float x) { return fast_rcp(1.0f + __expf(-x)); }
__device__ __forceinline__ float ftanh(float x) { return 1.0f - 2.0f * fast_rcp(1.0f + __expf(2.0f * x)); }

__global__ void pack_mfma(const float* __restrict__ wif, const float* __restrict__ whf,
                          const float* __restrict__ bif, const float* __restrict__ bhf,
                          const float* __restrict__ wib, const float* __restrict__ whb,
                          const float* __restrict__ bib, const float* __restrict__ bhb,
                          unsigned short* __restrict__ ws)
{
    const int gid = blockIdx.x * 256 + threadIdx.x;
    if (gid < 4096) {
        // gid = ((dir*4+set)*8+tile)*64 + lane  (exactly matches main-kernel frag index)
        const int dir = gid >> 11, rest = gid & 2047;
        const int set = rest >> 9, tile = (rest >> 6) & 7, lane = rest & 63;
        const int n = lane & 15, q = lane >> 4;
        const int r = tile * 16 + n;             // gate-row: r = g*32 + u
        const int g = r >> 5, u = r & 31;
        const bool valid = (u < 24);
        const float* Wx = dir ? wib : wif;
        const float* Wh = dir ? whb : whf;
        const int row = g * 24 + u;              // original weight row (i,f,g,o blocks of 24)
        unsigned short vals[8];
        #pragma unroll
        for (int j = 0; j < 8; ++j) {
            const int k = q * 8 + j;             // K-slot within the chunk
            unsigned short o = 0;
            if (valid) {
                if (set < 2) {                   // x-weight sets
                    const int f = (k < 14) ? k : ((k < 28) ? k - 14 : -1);
                    if (f >= 0) {
                        const float w = Wx[row * IN_F + f];
                        const unsigned short hi = bf16_rne(w);
                        o = (set == 0) ? hi : bf16_rne(w - bf16_to_f(hi));
                    }
                } else {                         // h-weight sets
                    if (k < 24) {
                        const float w = Wh[row * H + k];
                        const unsigned short hi = bf16_rne(w);
                        o = (set == 2) ? hi : bf16_rne(w - bf16_to_f(hi));
                    }
                }
            }
            vals[j] = o;
        }
        unsigned short* d = ws + (size_t)gid * 8;
        #pragma unroll
        for (int j = 0; j < 8; ++j) d[j] = vals[j];
    } else if (gid < 4096 + 256) {
        const int idx = gid - 4096;
        const int dir = idx >> 7, r = idx & 127;
        const int g = r >> 5, u = r & 31;
        const float v = (u < 24)
            ? ((dir ? bib : bif)[g * 24 + u] + (dir ? bhb : bhf)[g * 24 + u]) : 0.0f;
        ((float*)ws)[16384 + dir * 128 + r] = v;
    }
}

// LDS arena (34816 B -> 4 blocks/CU):
//   xs  [0 .. 26624): x A-frag staging: ((wave*13 + s)*4 + q)*256 + e*16, 16 B per (q,e)
//       slots: [x_hi(14) | x_lo(14) | 0,0,0,0] as bf16
//   hst [26624 .. 34816): h staging, double buffered:
//       byte = 26624 + buf*4096 + wave*2048 + (half*4 + qpart)*256 + e*16 + (u&7)*2
//       half 0 = h_hi, 1 = h_lo; qpart = u>>3
__global__ __launch_bounds__(128, 2)
void bilstm_mfma(const float* __restrict__ x, const unsigned short* __restrict__ wpk,
                 const float* __restrict__ head_w, const float* __restrict__ head_b,
                 float* __restrict__ out, int B)
{
    __align__(16) __shared__ unsigned char arena[34816];

    const int tid  = threadIdx.x;
    const int wave = __builtin_amdgcn_readfirstlane(tid >> 6);   // 0 = fwd, 1 = bwd
    const int lane = tid & 63;
    const int q    = lane >> 4;        // quad group (K-slot group / m-row group)
    const int col  = lane & 15;        // n (gate-row col) in C; e (elem) in A
    const int b0   = blockIdx.x * 16;

    // ---- resident B-fragments (128 VGPRs) + bias ----
    frag8 Bf[4][8];
    #pragma unroll
    for (int s = 0; s < 4; ++s)
        #pragma unroll
        for (int t = 0; t < 8; ++t)
            Bf[s][t] = ((const frag8*)wpk)[((wave * 4 + s) * 8 + t) * 64 + lane];

    const float* wbias = (const float*)wpk + 16384 + wave * 128;
    float bias_v[8];
    #pragma unroll
    for (int t = 0; t < 8; ++t) bias_v[t] = wbias[t * 16 + col];

    // ---- x prefill: split to bf16 hi/lo, stage all 13 steps ----
    for (int rr = lane; rr < NSTEP * 16; rr += 64) {
        const int si = rr >> 4, e = rr & 15;
        const int t = wave ? (T_STEPS - 1 - si) : si;
        const float* xr = x + ((size_t)(b0 + e) * T_STEPS + t) * IN_F;
        float xv[IN_F];
        #pragma unroll
        for (int i = 0; i < 7; ++i) { f2 v = *(const f2*)(xr + 2 * i); xv[2*i] = v.x; xv[2*i+1] = v.y; }
        unsigned short sl[32];
        #pragma unroll
        for (int i = 0; i < IN_F; ++i) {
            const unsigned short hi = bf16_rne(xv[i]);
            sl[i] = hi;
            sl[IN_F + i] = bf16_rne(xv[i] - bf16_to_f(hi));
        }
        sl[28] = sl[29] = sl[30] = sl[31] = 0;
        #pragma unroll
        for (int qq = 0; qq < 4; ++qq) {
            u4 w;
            #pragma unroll
            for (int i = 0; i < 4; ++i)
                w[i] = (unsigned int)sl[qq*8 + 2*i] | ((unsigned int)sl[qq*8 + 2*i + 1] << 16);
            *(u4*)(arena + ((wave * NSTEP + si) * 4 + qq) * 256 + e * 16) = w;
        }
    }
    // zero h buffer 0 (h0 = 0)
    {
        unsigned int* hz = (unsigned int*)(arena + 26624 + wave * 2048);
        for (int i = lane; i < 512; i += 64) hz[i] = 0;
    }
    __syncthreads();

    // ---- recurrence ----
    float c_st[2][4];
    #pragma unroll
    for (int p = 0; p < 2; ++p)
        #pragma unroll
        for (int r = 0; r < 4; ++r) c_st[p][r] = 0.0f;

    const unsigned char* xrd = arena + (wave * NSTEP * 4 + q) * 256 + col * 16;
    const unsigned char* hrd = arena + 26624 + wave * 2048 + q * 256 + col * 16;
    unsigned char* hwr = arena + 26624 + wave * 2048 + (col >> 3) * 256 + (col & 7) * 2 + q * 64;

    #pragma unroll 1
    for (int s = 0; s < NSTEP; ++s) {
        const int boff = (s & 1) * 4096;          // read buffer
        const int woff = boff ^ 4096;             // write buffer

        const frag8 Ax  = *(const frag8*)(xrd + s * 1024);
        const frag8 Ahh = *(const frag8*)(hrd + boff);
        const frag8 Ahl = *(const frag8*)(hrd + boff + 1024);

        f4 acc[8];
        #pragma unroll
        for (int t = 0; t < 8; ++t) { const float b = bias_v[t]; acc[t] = (f4){b, b, b, b}; }

        #pragma unroll
        for (int t = 0; t < 8; ++t) {
            acc[t] = __builtin_amdgcn_mfma_f32_16x16x32_bf16(Ax,  Bf[0][t], acc[t], 0, 0, 0);
            acc[t] = __builtin_amdgcn_mfma_f32_16x16x32_bf16(Ax,  Bf[1][t], acc[t], 0, 0, 0);
            acc[t] = __builtin_amdgcn_mfma_f32_16x16x32_bf16(Ahh, Bf[2][t], acc[t], 0, 0, 0);
            acc[t] = __builtin_amdgcn_mfma_f32_16x16x32_bf16(Ahl, Bf[2][t], acc[t], 0, 0, 0);
            acc[t] = __builtin_amdgcn_mfma_f32_16x16x32_bf16(Ahh, Bf[3][t], acc[t], 0, 0, 0);
        }

        // activations + h write (tiles: i = 0+p, f = 2+p, g = 4+p, o = 6+p)
        unsigned char* hw = hwr + woff;
        #pragma unroll
        for (int p = 0; p < 2; ++p) {
            #pragma unroll
            for (int r = 0; r < 4; ++r) {
                const float iv = acc[0 + p][r], fv = acc[2 + p][r];
                const float gv = acc[4 + p][r], ov = acc[6 + p][r];
                const float ig = fsig(iv), fg = fsig(fv), gg = ftanh(gv), og = fsig(ov);
                const float cn = fg * c_st[p][r] + ig * gg;
                c_st[p][r] = cn;
                const float h = og * ftanh(cn);
                const unsigned short hh = bf16_rne(h);
                const unsigned short hl = bf16_rne(h - bf16_to_f(hh));
                *(unsigned short*)(hw + p * 512 + r * 16)        = hh;   // half 0
                *(unsigned short*)(hw + p * 512 + r * 16 + 1024) = hl;   // half 1
            }
        }
        __syncthreads();
    }

    // ---- head: final h is in buffer (13&1) = 1 ----
    if (tid < 64) {
        const int e = tid >> 2, cls = tid & 3;
        float acc = head_b[cls];
        const unsigned char* hb1 = arena + 26624 + 4096;
        #pragma unroll
        for (int u = 0; u < H; ++u) {
            const int off = ((u >> 3) * 256) + e * 16 + (u & 7) * 2;
            const float hf = bf16_to_f(*(const unsigned short*)(hb1 + off))
                           + bf16_to_f(*(const unsigned short*)(hb1 + off + 1024));
            const float hbv = bf16_to_f(*(const unsigned short*)(hb1 + 2048 + off))
                            + bf16_to_f(*(const unsigned short*)(hb1 + 2048 + off + 1024));
            acc += hf * head_w[cls * 2 * H + u] + hbv * head_w[cls * 2 * H + H + u];
        }
        out[(size_t)b0 * 4 + tid] = acc;   // (b0+e)*4 + cls == b0*4 + tid
    }
}

extern "C" void kernel_launch(void* const* d_in, const int* in_sizes, int n_in,
                              void* d_out, int out_size, void* d_ws, size_t ws_size,
                              hipStream_t stream)
{
    const float* x      = (const float*)d_in[0];
    const float* w_ih_f = (const float*)d_in[1];
    const float* w_hh_f = (const float*)d_in[2];
    const float* b_ih_f = (const float*)d_in[3];
    const float* b_hh_f = (const float*)d_in[4];
    const float* w_ih_b = (const float*)d_in[5];
    const float* w_hh_b = (const float*)d_in[6];
    const float* b_ih_b = (const float*)d_in[7];
    const float* b_hh_b = (const float*)d_in[8];
    const float* head_w = (const float*)d_in[9];
    const float* head_b = (const float*)d_in[10];
    float* out = (float*)d_out;
    unsigned short* ws = (unsigned short*)d_ws;

    const int B = in_sizes[0] / (T_STEPS * IN_F);

    hipLaunchKernelGGL(pack_mfma, dim3(17), dim3(256), 0, stream,
                       w_ih_f, w_hh_f, b_ih_f, b_hh_f,
                       w_ih_b, w_hh_b, b_ih_b, b_hh_b, ws);
    hipLaunchKernelGGL(bilstm_mfma, dim3((B + 15) / 16), dim3(128), 0, stream,
                       x, ws, head_w, head_b, out, B);
}